// Round 19
// baseline (157.671 us; speedup 1.0000x reference)
//
#include <hip/hip_runtime.h>
#include <hip/hip_bf16.h>
#include <math.h>

#define N_FEAT 32
#define N_HID  64   // 2*N_FEAT
#define N_LAT  64
#define R_HID  128  // 2*N_LAT
#define TILES_PER_WAVE 32   // 512 tracks/wave -> 3907 waves (r17-validated;
                            // 0.95x of the 4096 residency slots = sweet spot)
#define STREAM (4 * TILES_PER_WAVE)   // 128 contiguous tracks per lane-group
#define H1W 88              // h1 bf16 row stride in shorts (176B, aligned b128 rows)
#define R1W 136             // r1 bf16 row stride in shorts (272B, b128-aligned rows)
#define RTPW 4              // rho: event-tiles per wave (r18-validated)

typedef short s16x8 __attribute__((ext_vector_type(8)));
typedef short s16x4 __attribute__((ext_vector_type(4)));
typedef float f32x4 __attribute__((ext_vector_type(4)));
typedef float f32x2 __attribute__((ext_vector_type(2)));
typedef int   i32x4 __attribute__((ext_vector_type(4)));

__device__ __forceinline__ short bfs(float f) {          // f32 -> bf16 bits (RNE)
    __bf16 b = (__bf16)f;
    return __builtin_bit_cast(short, b);
}
__device__ __forceinline__ float bff(short s) {          // bf16 bits -> f32 (exact)
    return (float)__builtin_bit_cast(__bf16, s);
}
__device__ __forceinline__ f32x4 mfma16(s16x8 a, s16x8 b, f32x4 c) {
    return __builtin_amdgcn_mfma_f32_16x16x32_bf16(a, b, c, 0, 0, 0);
}
__device__ __forceinline__ void split8(f32x4 a, f32x4 b, s16x8& h, s16x8& l) {
    #pragma unroll
    for (int j = 0; j < 4; ++j) {
        short h0 = bfs(a[j]); h[j] = h0;     l[j] = bfs(a[j] - bff(h0));
        short h1 = bfs(b[j]); h[4 + j] = h1; l[4 + j] = bfs(b[j] - bff(h1));
    }
}
__device__ __forceinline__ s16x8 pack8(f32x4 a, f32x4 b) {   // hi-only
    s16x8 h;
    #pragma unroll
    for (int j = 0; j < 4; ++j) { h[j] = bfs(a[j]); h[4 + j] = bfs(b[j]); }
    return h;
}

// packed 2xf32 atomic add (gfx90a+/CDNA4 global_atomic_pk_add_f32). Same f32
// adds as two scalar atomics (bit-identical result), half the instructions.
__device__ __forceinline__ void atomic_pk_add2(float* p, float a, float b) {
#if __has_builtin(__builtin_amdgcn_global_atomic_fadd_v2f32)
    f32x2 v; v[0] = a; v[1] = b;
    __builtin_amdgcn_global_atomic_fadd_v2f32(
        (__attribute__((address_space(1))) f32x2*)p, v);
#else
    atomicAdd(p, a);
    atomicAdd(p + 1, b);
#endif
}

// B-frag loader: lane (g,r), tile col c: b[j] = w[(k0+j)*64 + c], split hi/lo.
__device__ __forceinline__ void load_bfrag(const float* __restrict__ w, int k0, int c,
                                           s16x8& hi, s16x8& lo) {
    #pragma unroll
    for (int j = 0; j < 8; ++j) {
        float f = w[(size_t)(k0 + j) * 64 + c];
        short h = bfs(f);
        hi[j] = h;
        lo[j] = bfs(f - bff(h));
    }
}

// ---------------------------------------------------------------------------
// Fast zero of the pooled accumulator (in-graph; ~5 us at HBM write BW).
// ---------------------------------------------------------------------------
__global__ __launch_bounds__(256) void zero_kernel(f32x4* __restrict__ p, int n4)
{
    int i = blockIdx.x * blockDim.x + threadIdx.x;
    int stride = gridDim.x * blockDim.x;
    f32x4 z = {0.f, 0.f, 0.f, 0.f};
    for (; i < n4; i += stride) p[i] = z;
}

// ---------------------------------------------------------------------------
// phi via bf16 MFMA. Round-19 change: W2-frag COLUMN REMAP (frag n <- W2 col
// 4r+n, bijective -- the frag->col assignment is free, r15-proven trick) so
// each lane's four h2/carry values are CONSECUTIVE pooled columns, flushed
// with 2x global_atomic_pk_add_f32 (8B packed) instead of 4x scalar f32
// atomics at stride-16. Halves the flush instruction count / dependency
// chain -- the only path that has ever moved phi (r11: -58%, r17: -7%).
// Same f32 adds in same order -> absmax must stay exactly 0.00390625.
// L1: xh x W1-hi/lo = 8 MFMA (W1 col 4r+n remap, b64 staging); h1 bf16 via
// LDS; L2: 16 MFMA. TILES=32, branch-free steady loop, 2-deep prefetch.
// MFMA layouts (m89/m91-verified): A: row=l&15, k=8*(l>>4)+j; B: col=l&15,
// k=8*(l>>4)+j; C/D: col=l&15, row=4*(l>>4)+reg.
// ---------------------------------------------------------------------------
__global__ __launch_bounds__(256, 4) void phi_mfma_kernel(
    const float* __restrict__ x,
    const int*   __restrict__ eids,
    const float* __restrict__ w1, const float* __restrict__ b1,
    const float* __restrict__ w2, const float* __restrict__ b2,
    float* __restrict__ pooled, int n_tracks)
{
    __shared__ s16x8 wfrag[16][64];          // W2 frags: [4s+n]=hi, [8+4s+n]=lo
    __shared__ short h1s[4][16 * H1W];       // bf16 h1, per-wave slice

    const int lane = threadIdx.x & 63;
    const int wv   = threadIdx.x >> 6;
    const int g    = lane >> 4;
    const int r    = lane & 15;
    const int sg   = r >> 2;      // stream of A-row r
    const int so   = r & 3;       // offset within the stream's 4-track window

    // W2 pack with col remap: frag n covers TRUE column 4r+n (was r+16n)
    #pragma unroll
    for (int ff = 0; ff < 4; ++ff) {
        int f   = wv + 4 * ff;
        int idx = f & 7;
        int s   = idx >> 2;
        int n   = idx & 3;
        bool lo = (f >= 8);
        s16x8 v;
        #pragma unroll
        for (int j = 0; j < 8; ++j) {
            float fv = w2[(size_t)(32 * s + 8 * g + j) * 64 + (4 * r + n)];
            short h  = bfs(fv);
            v[j] = lo ? bfs(fv - bff(h)) : h;
        }
        wfrag[f][lane] = v;
    }
    __syncthreads();

    short* h1w = h1s[wv];
    const long long wbase = ((long long)blockIdx.x * 4 + wv) * (4LL * STREAM);
    if (wbase >= n_tracks) return;   // after the only barrier -> safe

    // W1 hi/lo frags in VGPRs (32 regs); tile n <- W1 column 4r+n (remap)
    s16x8 w1h[4], w1l[4];
    #pragma unroll
    for (int n = 0; n < 4; ++n) load_bfrag(w1, 8 * g, 4 * r + n, w1h[n], w1l[n]);

    float b1v[4], b2v[4];
    #pragma unroll
    for (int n = 0; n < 4; ++n) { b1v[n] = b1[4 * r + n]; b2v[n] = b2[4 * r + n]; }

    // x loader: A-row r of tile T <- track wbase + sg*STREAM + 4T + so
    #define LOADX(T, XA, XB) {                                                    \
        long long row_ = wbase + (long long)sg * STREAM + 4 * (T) + so;           \
        if (row_ > n_tracks - 1) row_ = n_tracks - 1;                             \
        XA = *(const f32x4*)(x + row_ * N_FEAT + 8 * g);                          \
        XB = *(const f32x4*)(x + row_ * N_FEAT + 8 * g + 4);                      \
    }
    // eid loader: group g's window for tile T
    #define LOADE(T, E4) {                                                        \
        long long ib_ = wbase + (long long)g * STREAM + 4 * (T);                  \
        if (ib_ > n_tracks - 4) ib_ = (n_tracks - 4) & ~3LL;                      \
        E4 = *(const i32x4*)(eids + ib_);                                         \
    }

    // ---- prologue: 2-deep prefetch pipe ----
    f32x4 xaA, xbA, xaB, xbB; i32x4 e4A, e4B;
    LOADX(0, xaA, xbA) LOADE(0, e4A)
    LOADX(1, xaB, xbB) LOADE(1, e4B)

    float carry[4] = {0.f, 0.f, 0.f, 0.f};
    int carry_id = -1;
    int dyn = 0;   // opaque 0: keeps wfrag reads per-tile (defeats LICM reg-hoist)

    // flush lane's 4 consecutive cols (4r..4r+3) with 2 packed atomics
    #define FLUSHC(EID) {                                                         \
        float* fp_ = pooled + (size_t)(EID) * N_LAT + 4 * r;                      \
        atomic_pk_add2(fp_,     carry[0], carry[1]);                              \
        atomic_pk_add2(fp_ + 2, carry[2], carry[3]);                              \
    }
    #define ZEROC() { carry[0] = 0.f; carry[1] = 0.f; carry[2] = 0.f; carry[3] = 0.f; }
    #define ADDQ(Q) {                                                             \
        _Pragma("unroll")                                                         \
        for (int n = 0; n < 4; ++n) {                                             \
            float fq_ = fmaxf(h2C[n][Q] + b2v[n], 0.f);                           \
            carry[n] += ((Q) < remg) ? fq_ : 0.f;                                 \
        }                                                                         \
    }

    // tile body; PF is a compile-time literal so the steady-state loop has
    // unconditional loads (no data-dependent branch on the load path)
    #define PHI_TILE(T, PF)                                                       \
    {                                                                             \
        asm volatile("" : "+v"(dyn));                                             \
        const s16x8* wfl = (const s16x8*)&wfrag[0][lane] + dyn;                   \
        long long tbg = wbase + (long long)g * STREAM + 4 * (T);                  \
        s16x8 xh = pack8(xaA, xbA);                                               \
        i32x4 e4c = e4A;                                                          \
        xaA = xaB; xbA = xbB; e4A = e4B;                                          \
        if (PF) { LOADX((T) + 2, xaB, xbB) LOADE((T) + 2, e4B) }                  \
        f32x4 h1C[4];                                                             \
        _Pragma("unroll")                                                         \
        for (int n = 0; n < 4; ++n) {                                             \
            f32x4 c = {0.f, 0.f, 0.f, 0.f};                                       \
            c = mfma16(xh, w1l[n], c);                                            \
            c = mfma16(xh, w1h[n], c);                                            \
            h1C[n] = c;                                                           \
        }                                                                         \
        _Pragma("unroll")                                                         \
        for (int q = 0; q < 4; ++q) {                                             \
            s16x4 v;                                                              \
            _Pragma("unroll")                                                     \
            for (int n = 0; n < 4; ++n)                                           \
                v[n] = bfs(fmaxf(h1C[n][q] + b1v[n], 0.f));                       \
            *(s16x4*)&h1w[(4 * g + q) * H1W + 4 * r] = v;                         \
        }                                                                         \
        s16x8 ah0 = *(const s16x8*)&h1w[r * H1W + 8 * g];                         \
        s16x8 ah1 = *(const s16x8*)&h1w[r * H1W + 32 + 8 * g];                    \
        f32x4 h2C[4] = {{0.f,0.f,0.f,0.f},{0.f,0.f,0.f,0.f},                      \
                        {0.f,0.f,0.f,0.f},{0.f,0.f,0.f,0.f}};                     \
        _Pragma("unroll")                                                         \
        for (int n = 0; n < 4; ++n) {                                             \
            h2C[n] = mfma16(ah0, wfl[64 * (8 + n)], h2C[n]);                      \
            h2C[n] = mfma16(ah0, wfl[64 * n],       h2C[n]);                      \
            h2C[n] = mfma16(ah1, wfl[64 * (12 + n)], h2C[n]);                     \
            h2C[n] = mfma16(ah1, wfl[64 * (4 + n)],  h2C[n]);                     \
        }                                                                         \
        int remg = (int)(n_tracks - tbg);                                         \
        remg = remg < 0 ? 0 : (remg > 4 ? 4 : remg);                              \
        const bool newrun   = (e4c[0] != carry_id);                               \
        const bool doflush0 = newrun && (carry_id >= 0);                          \
        const bool q01 = (e4c[1] != e4c[0]);                                      \
        const bool q12 = (e4c[2] != e4c[1]);                                      \
        const bool q23 = (e4c[3] != e4c[2]);                                      \
        if (doflush0) FLUSHC(carry_id)                                            \
        if (newrun)   ZEROC()                                                     \
        ADDQ(0)                                                                   \
        if (q01) { FLUSHC(e4c[0]) ZEROC() }                                       \
        ADDQ(1)                                                                   \
        if (q12) { FLUSHC(e4c[1]) ZEROC() }                                       \
        ADDQ(2)                                                                   \
        if (q23) { FLUSHC(e4c[2]) ZEROC() }                                       \
        ADDQ(3)                                                                   \
        carry_id = e4c[3];                                                        \
    }

    // steady state: branch-free loads (prefetch always legal, t+2 <= TILES-1)
    #pragma unroll 1
    for (int t = 0; t + 2 < TILES_PER_WAVE; ++t) {
        PHI_TILE(t, 1)
    }
    // peeled epilogue: no prefetch
    PHI_TILE(TILES_PER_WAVE - 2, 0)
    PHI_TILE(TILES_PER_WAVE - 1, 0)
    #undef PHI_TILE

    if (carry_id >= 0) FLUSHC(carry_id)
    #undef FLUSHC
    #undef ZEROC
    #undef ADDQ
    #undef LOADX
    #undef LOADE
}

// ---------------------------------------------------------------------------
// rho FUSED, MULTI-TILE (r18-validated, frozen): RTPW=4 tiles/wave; one
// weight prologue per 64 events; st staging reused per tile (same-wave DS
// in-order); A-frags buffered in regs. LDS 49.4 KB -> 3 blocks/CU.
// ---------------------------------------------------------------------------
__global__ __launch_bounds__(256, 3) void rho_fused_kernel(
    const float* __restrict__ pooled,
    const float* __restrict__ w1, const float* __restrict__ b1,
    const float* __restrict__ w2, const float* __restrict__ b2,
    const float* __restrict__ w3, const float* __restrict__ b3,
    float* __restrict__ out, int n_events)
{
    __shared__ s16x8 wf[32][64];            // W1 frags, then W2 frags (reused)
    __shared__ short st[4][16 * R1W];       // per-wave r1 staging (reused per tile)

    const int lane = threadIdx.x & 63;
    const int wv   = threadIdx.x >> 6;
    const int g    = lane >> 4;
    const int r    = lane & 15;

    const long long wbase = ((long long)blockIdx.x * 4 + wv) * (16 * RTPW);

    // ---- pack W1 frags: [plane*16 + ks*8 + nt] ----
    #pragma unroll
    for (int ff = 0; ff < 8; ++ff) {
        int f = wv + 4 * ff;
        int plane = f >> 4;                 // 0 hi, 1 lo
        int idx = f & 15;
        int ks = idx >> 3, nt = idx & 7;
        s16x8 v;
        #pragma unroll
        for (int j = 0; j < 8; ++j) {
            float fv = w1[(size_t)(32 * ks + 8 * g + j) * R_HID + (r + 16 * nt)];
            short h  = bfs(fv);
            v[j] = plane ? bfs(fv - bff(h)) : h;
        }
        wf[f][lane] = v;
    }
    __syncthreads();

    // ---- stage 1 x RTPW: r1 tiles -> st -> buffered A-frags in regs ----
    short* stw = st[wv];
    s16x8 ah[RTPW][4];
    #pragma unroll
    for (int t = 0; t < RTPW; ++t) {
        long long ebase = wbase + 16 * t;
        if (ebase < n_events) {
            long long prow = ebase + r; if (prow > n_events - 1) prow = n_events - 1;
            const f32x4* pr = (const f32x4*)(pooled + prow * N_LAT);
            s16x8 xh0, xl0, xh1, xl1;
            split8(pr[2 * g],     pr[2 * g + 1], xh0, xl0);
            split8(pr[8 + 2 * g], pr[9 + 2 * g], xh1, xl1);

            #pragma unroll
            for (int nt = 0; nt < 8; ++nt) {
                s16x8 wh0 = wf[nt][lane],      wl0 = wf[16 + nt][lane];
                s16x8 wh1 = wf[8 + nt][lane],  wl1 = wf[24 + nt][lane];
                f32x4 c = {0.f, 0.f, 0.f, 0.f};
                c = mfma16(xl0, wh0, c);
                c = mfma16(xh0, wl0, c);
                c = mfma16(xh0, wh0, c);
                c = mfma16(xl1, wh1, c);
                c = mfma16(xh1, wl1, c);
                c = mfma16(xh1, wh1, c);
                float bv = b1[r + 16 * nt];
                #pragma unroll
                for (int q = 0; q < 4; ++q)
                    stw[(4 * g + q) * R1W + r + 16 * nt] = bfs(fmaxf(c[q] + bv, 0.f));
            }
            #pragma unroll
            for (int ks = 0; ks < 4; ++ks)
                ah[t][ks] = *(const s16x8*)&stw[r * R1W + 32 * ks + 8 * g];
        }
    }
    __syncthreads();   // all waves done reading wf(W1)

    // ---- repack wf with W2 frags: [plane*16 + ks*4 + nt] ----
    #pragma unroll
    for (int ff = 0; ff < 8; ++ff) {
        int f = wv + 4 * ff;
        int plane = f >> 4;
        int idx = f & 15;
        int ks = idx >> 2, nt = idx & 3;
        s16x8 v;
        #pragma unroll
        for (int j = 0; j < 8; ++j) {
            float fv = w2[(size_t)(32 * ks + 8 * g + j) * N_LAT + (r + 16 * nt)];
            short h  = bfs(fv);
            v[j] = plane ? bfs(fv - bff(h)) : h;
        }
        wf[f][lane] = v;
    }
    __syncthreads();

    // ---- stage 2 x RTPW: 32 MFMA each; L3 reduce + sigmoid ----
    #pragma unroll
    for (int t = 0; t < RTPW; ++t) {
        long long ebase = wbase + 16 * t;
        if (ebase >= n_events) continue;

        float s0 = 0.f, s1 = 0.f, s2 = 0.f, s3 = 0.f;
        #pragma unroll
        for (int nt = 0; nt < 4; ++nt) {
            f32x4 c = {0.f, 0.f, 0.f, 0.f};
            #pragma unroll
            for (int ks = 0; ks < 4; ++ks) {
                c = mfma16(ah[t][ks], wf[16 + ks * 4 + nt][lane], c);   // lo
                c = mfma16(ah[t][ks], wf[ks * 4 + nt][lane],      c);   // hi
            }
            float bv = b2[r + 16 * nt];
            float wv3 = w3[r + 16 * nt];
            s0 = fmaf(fmaxf(c[0] + bv, 0.f), wv3, s0);
            s1 = fmaf(fmaxf(c[1] + bv, 0.f), wv3, s1);
            s2 = fmaf(fmaxf(c[2] + bv, 0.f), wv3, s2);
            s3 = fmaf(fmaxf(c[3] + bv, 0.f), wv3, s3);
        }
        #pragma unroll
        for (int off = 1; off < 16; off <<= 1) {
            s0 += __shfl_xor(s0, off, 64);
            s1 += __shfl_xor(s1, off, 64);
            s2 += __shfl_xor(s2, off, 64);
            s3 += __shfl_xor(s3, off, 64);
        }
        if (r == 0) {
            float b3v = b3[0];
            float zs[4] = {s0, s1, s2, s3};
            #pragma unroll
            for (int q = 0; q < 4; ++q) {
                long long e = ebase + 4 * g + q;
                if (e < n_events) out[e] = 1.f / (1.f + expf(-(zs[q] + b3v)));
            }
        }
    }
}

extern "C" void kernel_launch(void* const* d_in, const int* in_sizes, int n_in,
                              void* d_out, int out_size, void* d_ws, size_t ws_size,
                              hipStream_t stream) {
    const float* x      = (const float*)d_in[0];
    const int*   eids   = (const int*)  d_in[1];
    const float* phi_w1 = (const float*)d_in[2];
    const float* phi_b1 = (const float*)d_in[3];
    const float* phi_w2 = (const float*)d_in[4];
    const float* phi_b2 = (const float*)d_in[5];
    const float* rho_w1 = (const float*)d_in[6];
    const float* rho_b1 = (const float*)d_in[7];
    const float* rho_w2 = (const float*)d_in[8];
    const float* rho_b2 = (const float*)d_in[9];
    const float* rho_w3 = (const float*)d_in[10];
    const float* rho_b3 = (const float*)d_in[11];
    float* out = (float*)d_out;

    int n_tracks = in_sizes[1];
    int n_events = out_size;

    float* pooled = (float*)d_ws;   // 25.6 MB f32 accumulator

    int n4 = n_events * N_LAT / 4;
    zero_kernel<<<2048, 256, 0, stream>>>((f32x4*)pooled, n4);

    long long tracks_per_wave = 4LL * STREAM;   // 512
    long long waves  = ((long long)n_tracks + tracks_per_wave - 1) / tracks_per_wave;
    int phi_blocks   = (int)((waves + 3) / 4);
    phi_mfma_kernel<<<phi_blocks, 256, 0, stream>>>(
        x, eids, phi_w1, phi_b1, phi_w2, phi_b2, pooled, n_tracks);

    long long tiles  = ((long long)n_events + 15) / 16;              // 6250
    long long rwaves = (tiles + RTPW - 1) / RTPW;                    // 1563
    int rho_blocks   = (int)((rwaves + 3) / 4);                      // 391
    rho_fused_kernel<<<rho_blocks, 256, 0, stream>>>(
        pooled, rho_w1, rho_b1, rho_w2, rho_b2, rho_w3, rho_b3, out, n_events);
}

// Round 20
// 103.707 us; speedup vs baseline: 1.5204x; 1.5204x over previous
//
#include <hip/hip_runtime.h>
#include <hip/hip_bf16.h>
#include <math.h>

#define N_FEAT 32
#define N_HID  64   // 2*N_FEAT
#define N_LAT  64
#define R_HID  128  // 2*N_LAT
#define TILES_PER_WAVE 32   // 512 tracks/wave -> 3907 waves (r17-validated)
#define STREAM (4 * TILES_PER_WAVE)   // 128 contiguous tracks per lane-group
#define H1W 88              // h1 bf16 row stride in shorts (176B, aligned b128 rows)
#define R1W 136             // r1 bf16 row stride in shorts (272B, b128-aligned rows)
#define RTPW 4              // rho: event-tiles per wave (r18-validated)

typedef short s16x8 __attribute__((ext_vector_type(8)));
typedef short s16x4 __attribute__((ext_vector_type(4)));
typedef float f32x4 __attribute__((ext_vector_type(4)));
typedef int   i32x4 __attribute__((ext_vector_type(4)));

__device__ __forceinline__ short bfs(float f) {          // f32 -> bf16 bits (RNE)
    __bf16 b = (__bf16)f;
    return __builtin_bit_cast(short, b);
}
__device__ __forceinline__ float bff(short s) {          // bf16 bits -> f32 (exact)
    return (float)__builtin_bit_cast(__bf16, s);
}
__device__ __forceinline__ f32x4 mfma16(s16x8 a, s16x8 b, f32x4 c) {
    return __builtin_amdgcn_mfma_f32_16x16x32_bf16(a, b, c, 0, 0, 0);
}
__device__ __forceinline__ void split8(f32x4 a, f32x4 b, s16x8& h, s16x8& l) {
    #pragma unroll
    for (int j = 0; j < 4; ++j) {
        short h0 = bfs(a[j]); h[j] = h0;     l[j] = bfs(a[j] - bff(h0));
        short h1 = bfs(b[j]); h[4 + j] = h1; l[4 + j] = bfs(b[j] - bff(h1));
    }
}
__device__ __forceinline__ s16x8 pack8(f32x4 a, f32x4 b) {   // hi-only
    s16x8 h;
    #pragma unroll
    for (int j = 0; j < 4; ++j) { h[j] = bfs(a[j]); h[4 + j] = bfs(b[j]); }
    return h;
}

// B-frag loader: lane (g,r), tile col c: b[j] = w[(k0+j)*64 + c], split hi/lo.
__device__ __forceinline__ void load_bfrag(const float* __restrict__ w, int k0, int c,
                                           s16x8& hi, s16x8& lo) {
    #pragma unroll
    for (int j = 0; j < 8; ++j) {
        float f = w[(size_t)(k0 + j) * 64 + c];
        short h = bfs(f);
        hi[j] = h;
        lo[j] = bfs(f - bff(h));
    }
}

// ---------------------------------------------------------------------------
// Fast zero of the pooled accumulator (in-graph; ~5 us at HBM write BW).
// ---------------------------------------------------------------------------
__global__ __launch_bounds__(256) void zero_kernel(f32x4* __restrict__ p, int n4)
{
    int i = blockIdx.x * blockDim.x + threadIdx.x;
    int stride = gridDim.x * blockDim.x;
    f32x4 z = {0.f, 0.f, 0.f, 0.f};
    for (; i < n4; i += stride) p[i] = z;
}

// ---------------------------------------------------------------------------
// phi via bf16 MFMA (r17/r18-validated config -- REVERT of r19's packed-
// atomic experiment, which regressed 104->158 us: the W2-col remap broke the
// group-wide 16-lane unit-stride flush footprint, and the fadd_v2f32 builtin
// is value-RETURNING, so every flush serialized on the atomic round-trip.
// Lesson: fire-and-forget scalar global_atomic_add beats returning packed.)
// TILES=32, branch-free steady loop, 2-deep prefetch, W1 col 4r+n remap +
// b64 staging, contiguous-stream run-carry pooling with scalar atomics.
// absmax pinned at exactly 0.00390625 since r14.
// MFMA layouts (m89/m91-verified): A: row=l&15, k=8*(l>>4)+j; B: col=l&15,
// k=8*(l>>4)+j; C/D: col=l&15, row=4*(l>>4)+reg.
// ---------------------------------------------------------------------------
__global__ __launch_bounds__(256, 4) void phi_mfma_kernel(
    const float* __restrict__ x,
    const int*   __restrict__ eids,
    const float* __restrict__ w1, const float* __restrict__ b1,
    const float* __restrict__ w2, const float* __restrict__ b2,
    float* __restrict__ pooled, int n_tracks)
{
    __shared__ s16x8 wfrag[16][64];          // W2 frags: [4s+n]=hi, [8+4s+n]=lo
    __shared__ short h1s[4][16 * H1W];       // bf16 h1, per-wave slice

    const int lane = threadIdx.x & 63;
    const int wv   = threadIdx.x >> 6;
    const int g    = lane >> 4;
    const int r    = lane & 15;
    const int sg   = r >> 2;      // stream of A-row r
    const int so   = r & 3;       // offset within the stream's 4-track window

    #pragma unroll
    for (int ff = 0; ff < 4; ++ff) {
        int f   = wv + 4 * ff;
        int idx = f & 7;
        int s   = idx >> 2;
        int n   = idx & 3;
        bool lo = (f >= 8);
        s16x8 v;
        #pragma unroll
        for (int j = 0; j < 8; ++j) {
            float fv = w2[(size_t)(32 * s + 8 * g + j) * 64 + (r + 16 * n)];
            short h  = bfs(fv);
            v[j] = lo ? bfs(fv - bff(h)) : h;
        }
        wfrag[f][lane] = v;
    }
    __syncthreads();

    short* h1w = h1s[wv];
    const long long wbase = ((long long)blockIdx.x * 4 + wv) * (4LL * STREAM);
    if (wbase >= n_tracks) return;   // after the only barrier -> safe

    // W1 hi/lo frags in VGPRs (32 regs); tile n <- W1 column 4r+n (remap)
    s16x8 w1h[4], w1l[4];
    #pragma unroll
    for (int n = 0; n < 4; ++n) load_bfrag(w1, 8 * g, 4 * r + n, w1h[n], w1l[n]);

    float b1v[4], b2v[4];
    #pragma unroll
    for (int n = 0; n < 4; ++n) { b1v[n] = b1[4 * r + n]; b2v[n] = b2[r + 16 * n]; }

    // x loader: A-row r of tile T <- track wbase + sg*STREAM + 4T + so
    #define LOADX(T, XA, XB) {                                                    \
        long long row_ = wbase + (long long)sg * STREAM + 4 * (T) + so;           \
        if (row_ > n_tracks - 1) row_ = n_tracks - 1;                             \
        XA = *(const f32x4*)(x + row_ * N_FEAT + 8 * g);                          \
        XB = *(const f32x4*)(x + row_ * N_FEAT + 8 * g + 4);                      \
    }
    // eid loader: group g's window for tile T
    #define LOADE(T, E4) {                                                        \
        long long ib_ = wbase + (long long)g * STREAM + 4 * (T);                  \
        if (ib_ > n_tracks - 4) ib_ = (n_tracks - 4) & ~3LL;                      \
        E4 = *(const i32x4*)(eids + ib_);                                         \
    }

    // ---- prologue: 2-deep prefetch pipe ----
    f32x4 xaA, xbA, xaB, xbB; i32x4 e4A, e4B;
    LOADX(0, xaA, xbA) LOADE(0, e4A)
    LOADX(1, xaB, xbB) LOADE(1, e4B)

    float carry[4] = {0.f, 0.f, 0.f, 0.f};
    int carry_id = -1;
    int dyn = 0;   // opaque 0: keeps wfrag reads per-tile (defeats LICM reg-hoist)

    // tile body; PF is a compile-time literal so the steady-state loop has
    // unconditional loads (no data-dependent branch on the load path)
    #define PHI_TILE(T, PF)                                                       \
    {                                                                             \
        asm volatile("" : "+v"(dyn));                                             \
        const s16x8* wfl = (const s16x8*)&wfrag[0][lane] + dyn;                   \
        long long tbg = wbase + (long long)g * STREAM + 4 * (T);                  \
        s16x8 xh = pack8(xaA, xbA);                                               \
        i32x4 e4c = e4A;                                                          \
        xaA = xaB; xbA = xbB; e4A = e4B;                                          \
        if (PF) { LOADX((T) + 2, xaB, xbB) LOADE((T) + 2, e4B) }                  \
        f32x4 h1C[4];                                                             \
        _Pragma("unroll")                                                         \
        for (int n = 0; n < 4; ++n) {                                             \
            f32x4 c = {0.f, 0.f, 0.f, 0.f};                                       \
            c = mfma16(xh, w1l[n], c);                                            \
            c = mfma16(xh, w1h[n], c);                                            \
            h1C[n] = c;                                                           \
        }                                                                         \
        _Pragma("unroll")                                                         \
        for (int q = 0; q < 4; ++q) {                                             \
            s16x4 v;                                                              \
            _Pragma("unroll")                                                     \
            for (int n = 0; n < 4; ++n)                                           \
                v[n] = bfs(fmaxf(h1C[n][q] + b1v[n], 0.f));                       \
            *(s16x4*)&h1w[(4 * g + q) * H1W + 4 * r] = v;                         \
        }                                                                         \
        s16x8 ah0 = *(const s16x8*)&h1w[r * H1W + 8 * g];                         \
        s16x8 ah1 = *(const s16x8*)&h1w[r * H1W + 32 + 8 * g];                    \
        f32x4 h2C[4] = {{0.f,0.f,0.f,0.f},{0.f,0.f,0.f,0.f},                      \
                        {0.f,0.f,0.f,0.f},{0.f,0.f,0.f,0.f}};                     \
        _Pragma("unroll")                                                         \
        for (int n = 0; n < 4; ++n) {                                             \
            h2C[n] = mfma16(ah0, wfl[64 * (8 + n)], h2C[n]);                      \
            h2C[n] = mfma16(ah0, wfl[64 * n],       h2C[n]);                      \
            h2C[n] = mfma16(ah1, wfl[64 * (12 + n)], h2C[n]);                     \
            h2C[n] = mfma16(ah1, wfl[64 * (4 + n)],  h2C[n]);                     \
        }                                                                         \
        int remg = (int)(n_tracks - tbg);                                         \
        remg = remg < 0 ? 0 : (remg > 4 ? 4 : remg);                              \
        const bool newrun   = (e4c[0] != carry_id);                               \
        const bool doflush0 = newrun && (carry_id >= 0);                          \
        const bool q01 = (e4c[1] != e4c[0]);                                      \
        const bool q12 = (e4c[2] != e4c[1]);                                      \
        const bool q23 = (e4c[3] != e4c[2]);                                      \
        _Pragma("unroll")                                                         \
        for (int n = 0; n < 4; ++n) {                                             \
            f32x4 hv;                                                             \
            _Pragma("unroll")                                                     \
            for (int q = 0; q < 4; ++q) {                                         \
                float fq = fmaxf(h2C[n][q] + b2v[n], 0.f);                        \
                hv[q] = (q < remg) ? fq : 0.f;                                    \
            }                                                                     \
            float* pp = pooled + (size_t)(r + 16 * n);                            \
            float c = carry[n];                                                   \
            if (doflush0) atomicAdd(pp + (size_t)carry_id * N_LAT, c);            \
            if (newrun)   c = 0.f;                                                \
            c += hv[0];                                                           \
            if (q01) { atomicAdd(pp + (size_t)e4c[0] * N_LAT, c); c = 0.f; }      \
            c += hv[1];                                                           \
            if (q12) { atomicAdd(pp + (size_t)e4c[1] * N_LAT, c); c = 0.f; }      \
            c += hv[2];                                                           \
            if (q23) { atomicAdd(pp + (size_t)e4c[2] * N_LAT, c); c = 0.f; }      \
            c += hv[3];                                                           \
            carry[n] = c;                                                         \
        }                                                                         \
        carry_id = e4c[3];                                                        \
    }

    // steady state: branch-free loads (prefetch always legal, t+2 <= TILES-1)
    #pragma unroll 1
    for (int t = 0; t + 2 < TILES_PER_WAVE; ++t) {
        PHI_TILE(t, 1)
    }
    // peeled epilogue: no prefetch
    PHI_TILE(TILES_PER_WAVE - 2, 0)
    PHI_TILE(TILES_PER_WAVE - 1, 0)
    #undef PHI_TILE

    if (carry_id >= 0) {
        #pragma unroll
        for (int n = 0; n < 4; ++n)
            atomicAdd(pooled + (size_t)carry_id * N_LAT + r + 16 * n, carry[n]);
    }
    #undef LOADX
    #undef LOADE
}

// ---------------------------------------------------------------------------
// rho FUSED, MULTI-TILE (r18-validated, frozen): RTPW=4 tiles/wave; one
// weight prologue per 64 events; st staging reused per tile (same-wave DS
// in-order); A-frags buffered in regs. LDS 49.4 KB -> 3 blocks/CU.
// ---------------------------------------------------------------------------
__global__ __launch_bounds__(256, 3) void rho_fused_kernel(
    const float* __restrict__ pooled,
    const float* __restrict__ w1, const float* __restrict__ b1,
    const float* __restrict__ w2, const float* __restrict__ b2,
    const float* __restrict__ w3, const float* __restrict__ b3,
    float* __restrict__ out, int n_events)
{
    __shared__ s16x8 wf[32][64];            // W1 frags, then W2 frags (reused)
    __shared__ short st[4][16 * R1W];       // per-wave r1 staging (reused per tile)

    const int lane = threadIdx.x & 63;
    const int wv   = threadIdx.x >> 6;
    const int g    = lane >> 4;
    const int r    = lane & 15;

    const long long wbase = ((long long)blockIdx.x * 4 + wv) * (16 * RTPW);

    // ---- pack W1 frags: [plane*16 + ks*8 + nt] ----
    #pragma unroll
    for (int ff = 0; ff < 8; ++ff) {
        int f = wv + 4 * ff;
        int plane = f >> 4;                 // 0 hi, 1 lo
        int idx = f & 15;
        int ks = idx >> 3, nt = idx & 7;
        s16x8 v;
        #pragma unroll
        for (int j = 0; j < 8; ++j) {
            float fv = w1[(size_t)(32 * ks + 8 * g + j) * R_HID + (r + 16 * nt)];
            short h  = bfs(fv);
            v[j] = plane ? bfs(fv - bff(h)) : h;
        }
        wf[f][lane] = v;
    }
    __syncthreads();

    // ---- stage 1 x RTPW: r1 tiles -> st -> buffered A-frags in regs ----
    short* stw = st[wv];
    s16x8 ah[RTPW][4];
    #pragma unroll
    for (int t = 0; t < RTPW; ++t) {
        long long ebase = wbase + 16 * t;
        if (ebase < n_events) {
            long long prow = ebase + r; if (prow > n_events - 1) prow = n_events - 1;
            const f32x4* pr = (const f32x4*)(pooled + prow * N_LAT);
            s16x8 xh0, xl0, xh1, xl1;
            split8(pr[2 * g],     pr[2 * g + 1], xh0, xl0);
            split8(pr[8 + 2 * g], pr[9 + 2 * g], xh1, xl1);

            #pragma unroll
            for (int nt = 0; nt < 8; ++nt) {
                s16x8 wh0 = wf[nt][lane],      wl0 = wf[16 + nt][lane];
                s16x8 wh1 = wf[8 + nt][lane],  wl1 = wf[24 + nt][lane];
                f32x4 c = {0.f, 0.f, 0.f, 0.f};
                c = mfma16(xl0, wh0, c);
                c = mfma16(xh0, wl0, c);
                c = mfma16(xh0, wh0, c);
                c = mfma16(xl1, wh1, c);
                c = mfma16(xh1, wl1, c);
                c = mfma16(xh1, wh1, c);
                float bv = b1[r + 16 * nt];
                #pragma unroll
                for (int q = 0; q < 4; ++q)
                    stw[(4 * g + q) * R1W + r + 16 * nt] = bfs(fmaxf(c[q] + bv, 0.f));
            }
            #pragma unroll
            for (int ks = 0; ks < 4; ++ks)
                ah[t][ks] = *(const s16x8*)&stw[r * R1W + 32 * ks + 8 * g];
        }
    }
    __syncthreads();   // all waves done reading wf(W1)

    // ---- repack wf with W2 frags: [plane*16 + ks*4 + nt] ----
    #pragma unroll
    for (int ff = 0; ff < 8; ++ff) {
        int f = wv + 4 * ff;
        int plane = f >> 4;
        int idx = f & 15;
        int ks = idx >> 2, nt = idx & 3;
        s16x8 v;
        #pragma unroll
        for (int j = 0; j < 8; ++j) {
            float fv = w2[(size_t)(32 * ks + 8 * g + j) * N_LAT + (r + 16 * nt)];
            short h  = bfs(fv);
            v[j] = plane ? bfs(fv - bff(h)) : h;
        }
        wf[f][lane] = v;
    }
    __syncthreads();

    // ---- stage 2 x RTPW: 32 MFMA each; L3 reduce + sigmoid ----
    #pragma unroll
    for (int t = 0; t < RTPW; ++t) {
        long long ebase = wbase + 16 * t;
        if (ebase >= n_events) continue;

        float s0 = 0.f, s1 = 0.f, s2 = 0.f, s3 = 0.f;
        #pragma unroll
        for (int nt = 0; nt < 4; ++nt) {
            f32x4 c = {0.f, 0.f, 0.f, 0.f};
            #pragma unroll
            for (int ks = 0; ks < 4; ++ks) {
                c = mfma16(ah[t][ks], wf[16 + ks * 4 + nt][lane], c);   // lo
                c = mfma16(ah[t][ks], wf[ks * 4 + nt][lane],      c);   // hi
            }
            float bv = b2[r + 16 * nt];
            float wv3 = w3[r + 16 * nt];
            s0 = fmaf(fmaxf(c[0] + bv, 0.f), wv3, s0);
            s1 = fmaf(fmaxf(c[1] + bv, 0.f), wv3, s1);
            s2 = fmaf(fmaxf(c[2] + bv, 0.f), wv3, s2);
            s3 = fmaf(fmaxf(c[3] + bv, 0.f), wv3, s3);
        }
        #pragma unroll
        for (int off = 1; off < 16; off <<= 1) {
            s0 += __shfl_xor(s0, off, 64);
            s1 += __shfl_xor(s1, off, 64);
            s2 += __shfl_xor(s2, off, 64);
            s3 += __shfl_xor(s3, off, 64);
        }
        if (r == 0) {
            float b3v = b3[0];
            float zs[4] = {s0, s1, s2, s3};
            #pragma unroll
            for (int q = 0; q < 4; ++q) {
                long long e = ebase + 4 * g + q;
                if (e < n_events) out[e] = 1.f / (1.f + expf(-(zs[q] + b3v)));
            }
        }
    }
}

extern "C" void kernel_launch(void* const* d_in, const int* in_sizes, int n_in,
                              void* d_out, int out_size, void* d_ws, size_t ws_size,
                              hipStream_t stream) {
    const float* x      = (const float*)d_in[0];
    const int*   eids   = (const int*)  d_in[1];
    const float* phi_w1 = (const float*)d_in[2];
    const float* phi_b1 = (const float*)d_in[3];
    const float* phi_w2 = (const float*)d_in[4];
    const float* phi_b2 = (const float*)d_in[5];
    const float* rho_w1 = (const float*)d_in[6];
    const float* rho_b1 = (const float*)d_in[7];
    const float* rho_w2 = (const float*)d_in[8];
    const float* rho_b2 = (const float*)d_in[9];
    const float* rho_w3 = (const float*)d_in[10];
    const float* rho_b3 = (const float*)d_in[11];
    float* out = (float*)d_out;

    int n_tracks = in_sizes[1];
    int n_events = out_size;

    float* pooled = (float*)d_ws;   // 25.6 MB f32 accumulator

    int n4 = n_events * N_LAT / 4;
    zero_kernel<<<2048, 256, 0, stream>>>((f32x4*)pooled, n4);

    long long tracks_per_wave = 4LL * STREAM;   // 512
    long long waves  = ((long long)n_tracks + tracks_per_wave - 1) / tracks_per_wave;
    int phi_blocks   = (int)((waves + 3) / 4);
    phi_mfma_kernel<<<phi_blocks, 256, 0, stream>>>(
        x, eids, phi_w1, phi_b1, phi_w2, phi_b2, pooled, n_tracks);

    long long tiles  = ((long long)n_events + 15) / 16;              // 6250
    long long rwaves = (tiles + RTPW - 1) / RTPW;                    // 1563
    int rho_blocks   = (int)((rwaves + 3) / 4);                      // 391
    rho_fused_kernel<<<rho_blocks, 256, 0, stream>>>(
        pooled, rho_w1, rho_b1, rho_w2, rho_b2, rho_w3, rho_b3, out, n_events);
}